// Round 1
// baseline (294.503 us; speedup 1.0000x reference)
//
#include <hip/hip_runtime.h>
#include <hip/hip_fp16.h>
#include <stdint.h>

// Problem constants (fixed by reference file)
#define TOKENS 65536   // T*B = 2048*32
#define D      128
#define NEXP   9       // MULTI_INFER_NUM + 1
#define MT     128     // tokens per tile (block)
#define MAXTILES (TOKENS / MT + NEXP)  // 521 upper bound on sum ceil(cnt_e/MT)

typedef _Float16 f16;
typedef _Float16 f16x8  __attribute__((ext_vector_type(8)));
typedef float    f32x16 __attribute__((ext_vector_type(16)));
typedef uint32_t u32;

// ---- workspace layout (int indices unless noted) ----
// needs 262656 + 2359296 B ~= 2.5 MB of d_ws
#define WI_COUNTS  0    // [9]
#define WI_CURSOR  16   // [9]
#define WI_TOKOFF  32   // [10]
#define WI_TILEOFF 48   // [10]
#define WI_PERM    128  // [TOKENS]
#define WS_WT_BYTES ((128 + TOKENS) * 4)  // f16 Wt[2][4][9][128][128], 16B-aligned

__device__ __forceinline__ float sigm(float v) { return 1.0f / (1.0f + __expf(-v)); }
__device__ __forceinline__ float tanh_fast(float v) {
  // tanh(v) = 1 - 2/(exp(2v)+1); saturates correctly at +-inf
  return 1.0f - 2.0f / (__expf(2.0f * v) + 1.0f);
}

__device__ __forceinline__ void gld_lds16(const void* g, void* l) {
  __builtin_amdgcn_global_load_lds((const __attribute__((address_space(1))) u32*)g,
                                   (__attribute__((address_space(3))) u32*)l,
                                   16, 0, 0);
}

// ---- transpose + convert weights: Wt[l][g][e][f][d] = (f16)Ws[l][g][e][d][f] ----
__global__ void k_weights(const float* __restrict__ Ws, f16* __restrict__ Wt) {
  __shared__ __attribute__((aligned(16))) f16 tile[128 * 136];
  const float* src = Ws + (size_t)blockIdx.x * (D * D);
  f16* dst = Wt + (size_t)blockIdx.x * (D * D);
  for (int i = threadIdx.x; i < D * D; i += 256)
    tile[(i & 127) * 136 + (i >> 7)] = (f16)src[i];  // tile[f][d] = Ws[d][f]
  __syncthreads();
  for (int o = threadIdx.x; o < D * D; o += 256)
    dst[o] = tile[(o >> 7) * 136 + (o & 127)];
}

// ---- expert histogram ----
__global__ void k_hist(const int* __restrict__ pos, int* __restrict__ wsI) {
  __shared__ int h[NEXP];
  if (threadIdx.x < NEXP) h[threadIdx.x] = 0;
  __syncthreads();
  int t = blockIdx.x * 256 + threadIdx.x;
  int e = pos[t]; e = e < 8 ? e : 8;
  atomicAdd(&h[e], 1);
  __syncthreads();
  if (threadIdx.x < NEXP) atomicAdd(&wsI[WI_COUNTS + threadIdx.x], h[threadIdx.x]);
}

// ---- exclusive scans (token offsets + tile offsets) ----
__global__ void k_scan(int* wsI) {
  if (threadIdx.x == 0) {
    int tok = 0, tile = 0;
    wsI[WI_TOKOFF] = 0; wsI[WI_TILEOFF] = 0;
    for (int e = 0; e < NEXP; e++) {
      int cnt = wsI[WI_COUNTS + e];
      tok += cnt; tile += (cnt + MT - 1) / MT;
      wsI[WI_TOKOFF + e + 1] = tok;
      wsI[WI_TILEOFF + e + 1] = tile;
    }
  }
}

// ---- slot assignment (wave-aggregated atomics: 9 atomics/wave not 64) ----
__global__ void k_assign(const int* __restrict__ pos, int* __restrict__ wsI) {
  int t = blockIdx.x * 256 + threadIdx.x;
  int e = pos[t]; e = e < 8 ? e : 8;
  int lane = threadIdx.x & 63;
  int slotBase = 0, rank = 0;
  for (int ee = 0; ee < NEXP; ee++) {
    bool mine = (e == ee);
    unsigned long long m = __ballot(mine);
    if (m == 0ull) continue;                 // wave-uniform
    int leader = __ffsll(m) - 1;
    int cnt = __popcll(m);
    int base = 0;
    if (lane == leader) base = atomicAdd(&wsI[WI_CURSOR + ee], cnt);
    base = __shfl(base, leader);
    if (mine) { slotBase = base; rank = __popcll(m & ((1ull << lane) - 1ull)); }
  }
  wsI[WI_PERM + wsI[WI_TOKOFF + e] + slotBase + rank] = t;
}

// ---- fused: both layers, 4 gates, gating; one 128-token expert tile per block ----
__launch_bounds__(256, 2)
__global__ void k_main(const float* __restrict__ xin, const float* __restrict__ bsPtr,
                       const int* __restrict__ wsI, const f16* __restrict__ Wt,
                       float* __restrict__ outPtr) {
  __shared__ __attribute__((aligned(16))) f16 Ash[MT][144];   // row stride 144 f16 = 288B (16B aligned)
  __shared__ __attribute__((aligned(16))) f16 Bsh[2][4096];   // 2 x 8KB, fragment-major [kb][kh][n][8]
  __shared__ int s_tok[MT];

  const int tid = threadIdx.x;
  const int bid = blockIdx.x;
  const int ntiles = wsI[WI_TILEOFF + NEXP];
  if (bid >= ntiles) return;

  // tile -> (expert, token range)
  int e = 0, tileOffE = 0;
#pragma unroll
  for (int ee = 0; ee < NEXP; ee++) {
    int to = wsI[WI_TILEOFF + ee];
    if (to <= bid) { e = ee; tileOffE = to; }
  }
  const int tokStart = wsI[WI_TOKOFF + e] + (bid - tileOffE) * MT;
  const int tokEnd   = wsI[WI_TOKOFF + e + 1];
  const int rowsValid = min(MT, tokEnd - tokStart);

  // ---- stage A (layer-0 x) as f16, gather via perm; zero-fill invalid rows ----
  {
    int m = tid >> 1, h = tid & 1;
    bool valid = (m < rowsValid);
    int tok = 0;
    if (valid) tok = wsI[WI_PERM + tokStart + m];
    if (h == 0) s_tok[m] = valid ? tok : -1;
    const float4* src = (const float4*)(xin + (size_t)tok * D + h * 64);
    f16* drow = &Ash[m][h * 64];
#pragma unroll
    for (int i = 0; i < 8; i++) {
      float4 a = make_float4(0.f, 0.f, 0.f, 0.f), b = a;
      if (valid) { a = src[2 * i]; b = src[2 * i + 1]; }
      f16x8 w;
      w[0] = (f16)a.x; w[1] = (f16)a.y; w[2] = (f16)a.z; w[3] = (f16)a.w;
      w[4] = (f16)b.x; w[5] = (f16)b.y; w[6] = (f16)b.z; w[7] = (f16)b.w;
      *(f16x8*)&drow[i * 8] = w;
    }
  }

  // stage s = ((l*4 + c)*4 + j): stage B chunk [gate j, cols c*32..c*32+31] in frag-major order
  auto prefetchB = [&](int s, int buf) {
    int l = s >> 4, c = (s >> 2) & 3, j = s & 3;
    const f16* wb = Wt + (((size_t)(l * 4 + j) * NEXP + e) * (D * D));
#pragma unroll
    for (int p = 0; p < 2; p++) {
      int chunk = p * 256 + tid;          // 0..511, lane-consecutive => LDS base+lane*16
      int kb = chunk >> 6;
      int rem = chunk & 63;
      int khh = rem >> 5;
      int nn  = rem & 31;
      const f16* g = wb + ((c * 32 + nn) * D + kb * 16 + khh * 8);
      gld_lds16(g, &Bsh[buf][chunk * 8]);
    }
  };

  prefetchB(0, 0);
  __syncthreads();  // Ash ready for all waves

  const int lane = tid & 63;
  const int colN = lane & 31;       // MFMA n / C-col
  const int kh   = lane >> 5;       // K-half
  const int rowBase = (tid >> 6) * 32;

  f16x8 aF[8];
  f32x16 acc[4];

  for (int l = 0; l < 2; l++) {
    // A fragments for this layer (own wave's rows; in-wave DS ordering covers l=1)
    {
      int mA = rowBase + colN;
#pragma unroll
      for (int kb = 0; kb < 8; kb++)
        aF[kb] = *(const f16x8*)&Ash[mA][kb * 16 + kh * 8];
    }
    for (int c = 0; c < 4; c++) {
      const int f = c * 32 + colN;
      float bias[4];
#pragma unroll
      for (int j = 0; j < 4; j++)
        bias[j] = bsPtr[((size_t)(l * 4 + j) * NEXP + e) * D + f];

#pragma unroll
      for (int j = 0; j < 4; j++) {
        int s = (l * 4 + c) * 4 + j;
        __syncthreads();                       // buf[s&1] staged; buf[(s+1)&1] free
        if (s + 1 < 32) prefetchB(s + 1, (s + 1) & 1);
        const f16* bb = &Bsh[s & 1][0];
        f32x16 a;
#pragma unroll
        for (int i = 0; i < 16; i++) a[i] = 0.0f;
#pragma unroll
        for (int kb = 0; kb < 8; kb++) {
          f16x8 bF = *(const f16x8*)&bb[(kb * 2 + kh) * 256 + colN * 8];
          a = __builtin_amdgcn_mfma_f32_32x32x16_f16(aF[kb], bF, a, 0, 0, 0);
        }
        acc[j] = a;
      }

      // ---- gating epilogue for this 32-col chunk ----
#pragma unroll
      for (int r = 0; r < 16; r++) {
        int m = rowBase + (r & 3) + 8 * (r >> 2) + 4 * kh;  // C/D row mapping (m74/m101)
        float sf = acc[0][r] + bias[0];
        float lg = acc[1][r] + bias[1];
        float lf = acc[2][r] + bias[2];
        float of = acc[3][r] + bias[3];
        float xv = (float)Ash[m][f];
        float nr = xv * sigm(sf) + tanh_fast(lg) * sigm(lf);
        float xn = tanh_fast(nr) * sigm(of);
        if (l == 0) {
          Ash[m][f] = (f16)xn;             // becomes layer-1 A (own wave's rows only)
        } else {
          int tok = s_tok[m];
          if (tok >= 0) outPtr[(size_t)tok * D + f] = xn;
        }
      }
    }
  }
}

extern "C" void kernel_launch(void* const* d_in, const int* in_sizes, int n_in,
                              void* d_out, int out_size, void* d_ws, size_t ws_size,
                              hipStream_t stream) {
  const int*   pos = (const int*)d_in[0];
  const float* x   = (const float*)d_in[1];
  const float* Ws  = (const float*)d_in[2];
  const float* bs  = (const float*)d_in[3];
  float* out = (float*)d_out;
  int* wsI = (int*)d_ws;
  f16* Wt = (f16*)((char*)d_ws + WS_WT_BYTES);

  hipMemsetAsync(d_ws, 0, 512, stream);                 // counts + cursors
  k_weights<<<2 * 4 * NEXP, 256, 0, stream>>>(Ws, Wt);  // 72 matrices
  k_hist  <<<TOKENS / 256, 256, 0, stream>>>(pos, wsI);
  k_scan  <<<1, 64, 0, stream>>>(wsI);
  k_assign<<<TOKENS / 256, 256, 0, stream>>>(pos, wsI);
  k_main  <<<MAXTILES, 256, 0, stream>>>(x, bs, wsI, Wt, out);
}

// Round 2
// 161.625 us; speedup vs baseline: 1.8221x; 1.8221x over previous
//
#include <hip/hip_runtime.h>
#include <hip/hip_fp16.h>
#include <stdint.h>

// Problem constants (fixed by reference file)
#define TOKENS 65536   // T*B = 2048*32
#define D      128
#define NEXP   9       // MULTI_INFER_NUM + 1
#define MT     128     // tokens per tile (block)
#define MAXTILES (TOKENS / MT + NEXP)  // 521 upper bound on sum ceil(cnt_e/MT)
#define NHB    256     // hist blocks (TOKENS/256)

typedef _Float16 f16;
typedef _Float16 f16x8  __attribute__((ext_vector_type(8)));
typedef float    f32x16 __attribute__((ext_vector_type(16)));
typedef uint32_t u32;

// ---- workspace layout (int32 indices) ----
#define WI_TOKOFF  32            // [10]
#define WI_TILEOFF 48            // [10]
#define WI_HIST    128           // [256][9]
#define WI_BBASE   2432          // [256][9] absolute token base per (block,expert)
#define WI_PERM    4736          // [TOKENS]
#define WS_WF_OFF  ((4736 + TOKENS) * 4)   // f16 Wfrag[72][16384], 16B-aligned

__device__ __forceinline__ float sigm(float v) {
  return __builtin_amdgcn_rcpf(1.0f + __expf(-v));           // v_rcp_f32, not IEEE div
}
__device__ __forceinline__ float tanh_fast(float v) {
  return 1.0f - 2.0f * __builtin_amdgcn_rcpf(__expf(2.0f * v) + 1.0f);
}

// ---- fused prep: fragment-major f16 weights (blocks 0..287) + per-block expert hist (288..543) ----
// Wfrag[mat][c][kb][kh][n][i] = (f16) Ws[mat][d = kb*16+kh*8+i][f = c*32+n]
__global__ void k_prep(const float* __restrict__ Ws, const int* __restrict__ pos,
                       int* __restrict__ wsI, f16* __restrict__ Wf) {
  const int tid = threadIdx.x;
  if (blockIdx.x < 288) {
    const int mat = blockIdx.x >> 2;      // 0..71
    const int q   = blockIdx.x & 3;
    const float* src = Ws + (size_t)mat * (D * D);
    f16* dst = Wf + (size_t)mat * (D * D);
#pragma unroll
    for (int p = 0; p < 2; ++p) {
      int cc = q * 512 + p * 256 + tid;   // 16B chunk index 0..2047
      int n  = cc & 31;
      int khh = (cc >> 5) & 1;
      int kb = (cc >> 6) & 7;
      int c  = cc >> 9;
      int f  = c * 32 + n;
      int d0 = kb * 16 + khh * 8;
      f16x8 w;
#pragma unroll
      for (int i = 0; i < 8; ++i) w[i] = (f16)src[(d0 + i) * D + f];
      *(f16x8*)(dst + cc * 8) = w;
    }
  } else {
    const int b = blockIdx.x - 288;
    __shared__ int h[NEXP];
    if (tid < NEXP) h[tid] = 0;
    __syncthreads();
    int e = pos[b * 256 + tid]; e = e < 8 ? e : 8;
    atomicAdd(&h[e], 1);                  // LDS atomic — cheap
    __syncthreads();
    if (tid < NEXP) wsI[WI_HIST + b * NEXP + tid] = h[tid];
  }
}

// ---- one-block parallel scan: expert totals, token/tile offsets, per-block bases ----
__global__ void k_scan(int* __restrict__ wsI) {
  const int tid = threadIdx.x;            // 256 threads, tid == hist-block index
  const int lane = tid & 63, w = tid >> 6;
  __shared__ int wsum[4];
  __shared__ int totalsS[NEXP];
  __shared__ int tokoffS[NEXP + 1];
  int rel[NEXP];
  int myh[NEXP];
#pragma unroll
  for (int e = 0; e < NEXP; ++e) myh[e] = wsI[WI_HIST + tid * NEXP + e];

  for (int e = 0; e < NEXP; ++e) {
    int v = myh[e];
    int x = v;
#pragma unroll
    for (int off = 1; off < 64; off <<= 1) {
      int y = __shfl_up(x, off);
      if (lane >= off) x += y;
    }
    if (lane == 63) wsum[w] = x;
    __syncthreads();
    int add = 0;
    for (int w2 = 0; w2 < w; ++w2) add += wsum[w2];
    int incl = x + add;
    rel[e] = incl - v;                    // exclusive prefix over hist blocks
    if (tid == 255) totalsS[e] = incl;
    __syncthreads();
  }
  if (tid == 0) {
    int tok = 0, tile = 0;
    wsI[WI_TOKOFF] = 0; wsI[WI_TILEOFF] = 0; tokoffS[0] = 0;
    for (int e = 0; e < NEXP; ++e) {
      int cnt = totalsS[e];
      tok += cnt; tile += (cnt + MT - 1) / MT;
      wsI[WI_TOKOFF + e + 1] = tok;  tokoffS[e + 1] = tok;
      wsI[WI_TILEOFF + e + 1] = tile;
    }
  }
  __syncthreads();
#pragma unroll
  for (int e = 0; e < NEXP; ++e)
    wsI[WI_BBASE + tid * NEXP + e] = tokoffS[e] + rel[e];
}

// ---- assignment: ballot rank within wave, LDS wave offsets, zero global atomics ----
__global__ void k_assign(const int* __restrict__ pos, int* __restrict__ wsI) {
  const int tid = threadIdx.x, b = blockIdx.x;
  const int lane = tid & 63, w = tid >> 6;
  int e = pos[b * 256 + tid]; e = e < 8 ? e : 8;
  __shared__ int waveCnt[4][NEXP];
  __shared__ int waveBase[4][NEXP];
  int myRank = 0;
#pragma unroll
  for (int ee = 0; ee < NEXP; ++ee) {
    unsigned long long m = __ballot(e == ee);
    if (e == ee) myRank = __popcll(m & ((1ull << lane) - 1ull));
    if (lane == 0) waveCnt[w][ee] = __popcll(m);
  }
  __syncthreads();
  if (tid < NEXP) {
    int s = 0;
#pragma unroll
    for (int w2 = 0; w2 < 4; ++w2) { waveBase[w2][tid] = s; s += waveCnt[w2][tid]; }
  }
  __syncthreads();
  int base = wsI[WI_BBASE + b * NEXP + e];
  wsI[WI_PERM + base + waveBase[w][e] + myRank] = b * 256 + tid;
}

// ---- fused main: both layers, 4 gates, gating. B direct global->register (no K-loop barriers) ----
__launch_bounds__(256, 2)
__global__ void k_main(const float* __restrict__ xin, const float* __restrict__ bsPtr,
                       const int* __restrict__ wsI, const f16* __restrict__ Wf,
                       float* __restrict__ outPtr) {
  __shared__ __attribute__((aligned(16))) f16 Ash[MT][136];   // 272B row stride = 17*16B
  __shared__ int s_tok[MT];

  const int tid = threadIdx.x;
  const int bid = blockIdx.x;
  const int ntiles = wsI[WI_TILEOFF + NEXP];
  if (bid >= ntiles) return;

  // tile -> (expert, token range)
  int e = 0, tileOffE = 0;
#pragma unroll
  for (int ee = 0; ee < NEXP; ee++) {
    int to = wsI[WI_TILEOFF + ee];
    if (to <= bid) { e = ee; tileOffE = to; }
  }
  const int tokStart = wsI[WI_TOKOFF + e] + (bid - tileOffE) * MT;
  const int tokEnd   = wsI[WI_TOKOFF + e + 1];
  const int rowsValid = min(MT, tokEnd - tokStart);

  // ---- stage A (layer-0 x) as f16 via perm gather; zero-fill invalid rows ----
  {
    int m = tid >> 1, h = tid & 1;
    bool valid = (m < rowsValid);
    int tok = 0;
    if (valid) tok = wsI[WI_PERM + tokStart + m];
    if (h == 0) s_tok[m] = valid ? tok : -1;
    const float4* src = (const float4*)(xin + (size_t)tok * D + h * 64);
    f16* drow = &Ash[m][h * 64];
#pragma unroll
    for (int i = 0; i < 8; i++) {
      float4 a = make_float4(0.f, 0.f, 0.f, 0.f), b2 = a;
      if (valid) { a = src[2 * i]; b2 = src[2 * i + 1]; }
      f16x8 wv;
      wv[0] = (f16)a.x;  wv[1] = (f16)a.y;  wv[2] = (f16)a.z;  wv[3] = (f16)a.w;
      wv[4] = (f16)b2.x; wv[5] = (f16)b2.y; wv[6] = (f16)b2.z; wv[7] = (f16)b2.w;
      *(f16x8*)&drow[i * 8] = wv;
    }
  }
  __syncthreads();   // the ONLY block-wide barrier

  const int lane = tid & 63;
  const int colN = lane & 31;       // MFMA n / C-col
  const int kh   = lane >> 5;       // K-half
  const int rowBase = (tid >> 6) * 32;

  // B fragment address in fragment-major weights (perfectly lane-coalesced per kb)
  auto bAddr = [&](int l, int j, int c, int kb) -> const f16* {
    return Wf + ((l * 4 + j) * NEXP + e) * (D * D)
              + c * 4096 + (kb * 2 + kh) * 256 + colN * 8;
  };

  f16x8 aF[8];
  f16x8 bCur[8], bNxt[8];
  f32x16 acc[4];

#pragma unroll
  for (int kb = 0; kb < 8; ++kb) bCur[kb] = *(const f16x8*)bAddr(0, 0, 0, kb);

#pragma unroll
  for (int l = 0; l < 2; l++) {
    // A fragments (own wave's rows; ordered after epilogue ds_writes by lgkmcnt)
    {
      int mA = rowBase + colN;
#pragma unroll
      for (int kb = 0; kb < 8; kb++)
        aF[kb] = *(const f16x8*)&Ash[mA][kb * 16 + kh * 8];
    }
#pragma unroll
    for (int c = 0; c < 4; c++) {
      const int f = c * 32 + colN;
      float bias[4];
#pragma unroll
      for (int j = 0; j < 4; j++)
        bias[j] = bsPtr[((l * 4 + j) * NEXP + e) * D + f];

#pragma unroll
      for (int j = 0; j < 4; j++) {
        int s = (l * 4 + c) * 4 + j;
        if (s < 31) {                         // register prefetch of next stage's B
          int sn = s + 1;
          int l2 = sn >> 4, c2 = (sn >> 2) & 3, j2 = sn & 3;
#pragma unroll
          for (int kb = 0; kb < 8; ++kb) bNxt[kb] = *(const f16x8*)bAddr(l2, j2, c2, kb);
        }
        f32x16 a;
#pragma unroll
        for (int i = 0; i < 16; i++) a[i] = 0.0f;
#pragma unroll
        for (int kb = 0; kb < 8; kb++)
          a = __builtin_amdgcn_mfma_f32_32x32x16_f16(aF[kb], bCur[kb], a, 0, 0, 0);
        acc[j] = a;
#pragma unroll
        for (int kb = 0; kb < 8; ++kb) bCur[kb] = bNxt[kb];  // renamed away by unroll
      }

      // ---- gating epilogue for this 32-col chunk ----
#pragma unroll
      for (int r = 0; r < 16; r++) {
        int m = rowBase + (r & 3) + 8 * (r >> 2) + 4 * kh;  // C/D row mapping (m74/m101)
        float sf = acc[0][r] + bias[0];
        float lg = acc[1][r] + bias[1];
        float lf = acc[2][r] + bias[2];
        float of = acc[3][r] + bias[3];
        float xv = (float)Ash[m][f];
        float nr = xv * sigm(sf) + tanh_fast(lg) * sigm(lf);
        float xn = tanh_fast(nr) * sigm(of);
        if (l == 0) {
          Ash[m][f] = (f16)xn;             // becomes layer-1 A (own wave's rows only)
        } else {
          int tok = s_tok[m];
          if (tok >= 0) outPtr[(size_t)tok * D + f] = xn;
        }
      }
    }
  }
}

extern "C" void kernel_launch(void* const* d_in, const int* in_sizes, int n_in,
                              void* d_out, int out_size, void* d_ws, size_t ws_size,
                              hipStream_t stream) {
  const int*   pos = (const int*)d_in[0];
  const float* x   = (const float*)d_in[1];
  const float* Ws  = (const float*)d_in[2];
  const float* bs  = (const float*)d_in[3];
  float* out = (float*)d_out;
  int* wsI = (int*)d_ws;
  f16* Wf = (f16*)((char*)d_ws + WS_WF_OFF);

  k_prep  <<<544, 256, 0, stream>>>(Ws, pos, wsI, Wf);  // weights + hist (no memset needed)
  k_scan  <<<1, 256, 0, stream>>>(wsI);
  k_assign<<<NHB, 256, 0, stream>>>(pos, wsI);
  k_main  <<<MAXTILES, 256, 0, stream>>>(x, bs, wsI, Wf, out);
}